// Round 8
// baseline (155.467 us; speedup 1.0000x reference)
//
#include <hip/hip_runtime.h>

constexpr int SLN = 512, BSZ = 128, TAG = 32;
constexpr float INVLN2 = 1.4426950408889634f;
constexpr float LN2f = 0.6931471805599453f;

__device__ __forceinline__ float exp2_fast(float x) { return __builtin_amdgcn_exp2f(x); }
__device__ __forceinline__ float log2_fast(float x) { return __builtin_amdgcn_logf(x); }

__device__ __forceinline__ void pl16_swap(float& x, float& y) {
  asm("v_permlane16_swap_b32 %0, %1" : "+v"(x), "+v"(y));
}
__device__ __forceinline__ void pl32_swap(float& x, float& y) {
  asm("v_permlane32_swap_b32 %0, %1" : "+v"(x), "+v"(y));
}
// async global->LDS, 16B per lane
__device__ __forceinline__ void gload_lds16(const float* g, float* lds_uniform) {
  __builtin_amdgcn_global_load_lds(
      (const __attribute__((address_space(1))) unsigned int*)g,
      (__attribute__((address_space(3))) unsigned int*)lds_uniform, 16, 0, 0);
}

// ---- Variant A matvec (R7): 16 fused DPP FMAs, k split across row-pairs ----
__device__ __forceinline__ void matvecA(float& p0, float& p1, float& p2, float& p3,
                                        float ucur, const float (&E)[16]) {
  asm("s_nop 1\n\t"
      "v_mul_f32_dpp  %0, %4, %5  row_newbcast:0  row_mask:0xf bank_mask:0xf\n\t"
      "v_mul_f32_dpp  %1, %4, %6  row_newbcast:1  row_mask:0xf bank_mask:0xf\n\t"
      "v_mul_f32_dpp  %2, %4, %7  row_newbcast:2  row_mask:0xf bank_mask:0xf\n\t"
      "v_mul_f32_dpp  %3, %4, %8  row_newbcast:3  row_mask:0xf bank_mask:0xf\n\t"
      "v_fmac_f32_dpp %0, %4, %9  row_newbcast:4  row_mask:0xf bank_mask:0xf\n\t"
      "v_fmac_f32_dpp %1, %4, %10 row_newbcast:5  row_mask:0xf bank_mask:0xf\n\t"
      "v_fmac_f32_dpp %2, %4, %11 row_newbcast:6  row_mask:0xf bank_mask:0xf\n\t"
      "v_fmac_f32_dpp %3, %4, %12 row_newbcast:7  row_mask:0xf bank_mask:0xf\n\t"
      "v_fmac_f32_dpp %0, %4, %13 row_newbcast:8  row_mask:0xf bank_mask:0xf\n\t"
      "v_fmac_f32_dpp %1, %4, %14 row_newbcast:9  row_mask:0xf bank_mask:0xf\n\t"
      "v_fmac_f32_dpp %2, %4, %15 row_newbcast:10 row_mask:0xf bank_mask:0xf\n\t"
      "v_fmac_f32_dpp %3, %4, %16 row_newbcast:11 row_mask:0xf bank_mask:0xf\n\t"
      "v_fmac_f32_dpp %0, %4, %17 row_newbcast:12 row_mask:0xf bank_mask:0xf\n\t"
      "v_fmac_f32_dpp %1, %4, %18 row_newbcast:13 row_mask:0xf bank_mask:0xf\n\t"
      "v_fmac_f32_dpp %2, %4, %19 row_newbcast:14 row_mask:0xf bank_mask:0xf\n\t"
      "v_fmac_f32_dpp %3, %4, %20 row_newbcast:15 row_mask:0xf bank_mask:0xf"
      : "=&v"(p0), "=&v"(p1), "=&v"(p2), "=&v"(p3)
      : "v"(ucur), "v"(E[0]), "v"(E[1]), "v"(E[2]), "v"(E[3]), "v"(E[4]),
        "v"(E[5]), "v"(E[6]), "v"(E[7]), "v"(E[8]), "v"(E[9]), "v"(E[10]),
        "v"(E[11]), "v"(E[12]), "v"(E[13]), "v"(E[14]), "v"(E[15]));
}

// ---- Variant B matvec halves: full 32-term dot per lane, 2 blocks of 16 ----
__device__ __forceinline__ void matvecB_lo(float& p0, float& p1, float& p2, float& p3,
                                           float x, const float (&E)[16]) {
  asm("s_nop 1\n\t"
      "v_mul_f32_dpp  %0, %4, %5  row_newbcast:0  row_mask:0xf bank_mask:0xf\n\t"
      "v_mul_f32_dpp  %1, %4, %6  row_newbcast:1  row_mask:0xf bank_mask:0xf\n\t"
      "v_mul_f32_dpp  %2, %4, %7  row_newbcast:2  row_mask:0xf bank_mask:0xf\n\t"
      "v_mul_f32_dpp  %3, %4, %8  row_newbcast:3  row_mask:0xf bank_mask:0xf\n\t"
      "v_fmac_f32_dpp %0, %4, %9  row_newbcast:4  row_mask:0xf bank_mask:0xf\n\t"
      "v_fmac_f32_dpp %1, %4, %10 row_newbcast:5  row_mask:0xf bank_mask:0xf\n\t"
      "v_fmac_f32_dpp %2, %4, %11 row_newbcast:6  row_mask:0xf bank_mask:0xf\n\t"
      "v_fmac_f32_dpp %3, %4, %12 row_newbcast:7  row_mask:0xf bank_mask:0xf\n\t"
      "v_fmac_f32_dpp %0, %4, %13 row_newbcast:8  row_mask:0xf bank_mask:0xf\n\t"
      "v_fmac_f32_dpp %1, %4, %14 row_newbcast:9  row_mask:0xf bank_mask:0xf\n\t"
      "v_fmac_f32_dpp %2, %4, %15 row_newbcast:10 row_mask:0xf bank_mask:0xf\n\t"
      "v_fmac_f32_dpp %3, %4, %16 row_newbcast:11 row_mask:0xf bank_mask:0xf\n\t"
      "v_fmac_f32_dpp %0, %4, %17 row_newbcast:12 row_mask:0xf bank_mask:0xf\n\t"
      "v_fmac_f32_dpp %1, %4, %18 row_newbcast:13 row_mask:0xf bank_mask:0xf\n\t"
      "v_fmac_f32_dpp %2, %4, %19 row_newbcast:14 row_mask:0xf bank_mask:0xf\n\t"
      "v_fmac_f32_dpp %3, %4, %20 row_newbcast:15 row_mask:0xf bank_mask:0xf"
      : "=&v"(p0), "=&v"(p1), "=&v"(p2), "=&v"(p3)
      : "v"(x), "v"(E[0]), "v"(E[1]), "v"(E[2]), "v"(E[3]), "v"(E[4]),
        "v"(E[5]), "v"(E[6]), "v"(E[7]), "v"(E[8]), "v"(E[9]), "v"(E[10]),
        "v"(E[11]), "v"(E[12]), "v"(E[13]), "v"(E[14]), "v"(E[15]));
}
__device__ __forceinline__ void matvecB_hi(float& p0, float& p1, float& p2, float& p3,
                                           float y, const float (&E)[16]) {
  asm("v_fmac_f32_dpp %0, %4, %5  row_newbcast:0  row_mask:0xf bank_mask:0xf\n\t"
      "v_fmac_f32_dpp %1, %4, %6  row_newbcast:1  row_mask:0xf bank_mask:0xf\n\t"
      "v_fmac_f32_dpp %2, %4, %7  row_newbcast:2  row_mask:0xf bank_mask:0xf\n\t"
      "v_fmac_f32_dpp %3, %4, %8  row_newbcast:3  row_mask:0xf bank_mask:0xf\n\t"
      "v_fmac_f32_dpp %0, %4, %9  row_newbcast:4  row_mask:0xf bank_mask:0xf\n\t"
      "v_fmac_f32_dpp %1, %4, %10 row_newbcast:5  row_mask:0xf bank_mask:0xf\n\t"
      "v_fmac_f32_dpp %2, %4, %11 row_newbcast:6  row_mask:0xf bank_mask:0xf\n\t"
      "v_fmac_f32_dpp %3, %4, %12 row_newbcast:7  row_mask:0xf bank_mask:0xf\n\t"
      "v_fmac_f32_dpp %0, %4, %13 row_newbcast:8  row_mask:0xf bank_mask:0xf\n\t"
      "v_fmac_f32_dpp %1, %4, %14 row_newbcast:9  row_mask:0xf bank_mask:0xf\n\t"
      "v_fmac_f32_dpp %2, %4, %15 row_newbcast:10 row_mask:0xf bank_mask:0xf\n\t"
      "v_fmac_f32_dpp %3, %4, %16 row_newbcast:11 row_mask:0xf bank_mask:0xf\n\t"
      "v_fmac_f32_dpp %0, %4, %17 row_newbcast:12 row_mask:0xf bank_mask:0xf\n\t"
      "v_fmac_f32_dpp %1, %4, %18 row_newbcast:13 row_mask:0xf bank_mask:0xf\n\t"
      "v_fmac_f32_dpp %2, %4, %19 row_newbcast:14 row_mask:0xf bank_mask:0xf\n\t"
      "v_fmac_f32_dpp %3, %4, %20 row_newbcast:15 row_mask:0xf bank_mask:0xf"
      : "+v"(p0), "+v"(p1), "+v"(p2), "+v"(p3)
      : "v"(y), "v"(E[0]), "v"(E[1]), "v"(E[2]), "v"(E[3]), "v"(E[4]),
        "v"(E[5]), "v"(E[6]), "v"(E[7]), "v"(E[8]), "v"(E[9]), "v"(E[10]),
        "v"(E[11]), "v"(E[12]), "v"(E[13]), "v"(E[14]), "v"(E[15]));
}

// VAR 0 (R7): ucur rows [A,A,B,B]; matvec -> pl32 combine -> *emf -> pl16+sel rebuild.
// VAR 1 (new): state a[j] rows [J0,J1,J0,J1]; ONE pl16_swap yields lo/hi broadcast
//              sources; 32 DPP-FMAs -> full dot per lane -> *emf. No combine/rebuild.
template <int VAR>
__device__ __forceinline__ float crf_step(float s, const float (&EX)[16],
                                          const float (&EY)[16], float emf, bool selx) {
  if constexpr (VAR == 0) {
    float p0, p1, p2, p3;
    matvecA(p0, p1, p2, p3, s, EX);
    float x = (p0 + p1) + (p2 + p3), y = x;
    pl32_swap(x, y);
    const float a = (x + y) * emf;
    float xx = a, yy = a;
    pl16_swap(xx, yy);
    return selx ? xx : yy;
  } else {
    float x = s, y = s;
    pl16_swap(x, y);               // x,y = {lo-expand, hi-expand}; roles folded into EX/EY
    float p0, p1, p2, p3;
    matvecB_lo(p0, p1, p2, p3, x, EX);
    matvecB_hi(p0, p1, p2, p3, y, EY);
    return ((p0 + p1) + (p2 + p3)) * emf;
  }
}

// scan for batches [batch_base, batch_base+NSCAN); blocks beyond NSCAN do the
// gold-path score for batch (blk - NSCAN) when SCORE.
template <int VAR, int NSCAN, bool SCORE>
__global__ __launch_bounds__(64, 1) void crf_fwd(
    const float* __restrict__ emission, const int* __restrict__ length,
    const int* __restrict__ target, const float* __restrict__ transition,
    const float* __restrict__ start_tr, const float* __restrict__ end_tr,
    float* __restrict__ ws, int batch_base) {
  const int blk = blockIdx.x;
  const int lane = threadIdx.x;
  __shared__ float smem[SLN * TAG];

  if (blk < NSCAN) {
    const int b = batch_base + blk;

    const float* gembase = emission + (size_t)b * SLN * TAG;
    {
      const float* gl = gembase + lane * 4;
#pragma unroll
      for (int i = 0; i < 64; ++i)
        gload_lds16(gl + i * 256, &smem[i * 256]);
    }

    const int len = length[b];                       // [2, 512]
    const int r = lane >> 4;
    const int j = (lane & 15) + 16 * (r & 1);        // rows [J0,J1,J0,J1]

    // probe permlane16_swap output ordering
    int pv = lane, qv = lane;
    asm("v_permlane16_swap_b32 %0, %1" : "+v"(pv), "+v"(qv));
    const bool even_first = (__builtin_amdgcn_readfirstlane(pv) == 0);

    float EX[16], EY[16];
    bool selx = false;
    if constexpr (VAR == 0) {
      const int kh = lane >> 5;
#pragma unroll
      for (int n = 0; n < 16; ++n)
        EX[n] = exp2_fast(transition[(16 * kh + n) * TAG + j] * INVLN2);
      selx = (lane < 32) == even_first;
    } else {
      // EX pairs with the lo-expand register (x if even_first); wave-uniform branch
#pragma unroll
      for (int n = 0; n < 16; ++n) {
        const float ea = exp2_fast(transition[n * TAG + j] * INVLN2);
        const float eb = exp2_fast(transition[(16 + n) * TAG + j] * INVLN2);
        EX[n] = even_first ? ea : eb;
        EY[n] = even_first ? eb : ea;
      }
    }
    const float st = start_tr[j];

    asm volatile("s_waitcnt vmcnt(0)" ::: "memory"); // staging done (single wave)

    float base = 0.f;
    float ucur;
    {
      const float a0 = exp2_fast((st + smem[j]) * INVLN2);  // j-layout
      if constexpr (VAR == 0) {
        float xx = a0, yy = a0;
        pl16_swap(xx, yy);
        ucur = selx ? xx : yy;       // [A,A,B,B]
      } else {
        ucur = a0;                   // state IS j-layout
      }
    }

    float bufP[8], bufQ[8], emfP[8], emfQ[8];
#pragma unroll
    for (int u = 0; u < 8; ++u) {
      bufP[u] = smem[(1 + u) * TAG + j];
      emfP[u] = exp2_fast(bufP[u] * INVLN2);
    }

    const int steps = len - 1;
    const int nfull = steps >> 3;
    const int tail = steps & 7;
    const int npair = nfull >> 1;

    auto renorm = [&]() {
      const unsigned ab = (unsigned)__builtin_amdgcn_readfirstlane(__float_as_int(ucur));
      const int e = (int)((ab >> 23) & 255u) - 127;
      ucur *= __int_as_float((127 - e) << 23);
      base += (float)e;
    };

    auto do_block = [&](const float (&emfC)[8], float (&bufN)[8], float (&emfN)[8],
                        int t0) {
#pragma unroll
      for (int u = 0; u < 8; ++u) {
        int tp = t0 + 8 + u; tp = tp < SLN ? tp : SLN - 1;
        bufN[u] = smem[tp * TAG + j];
      }
      __builtin_amdgcn_sched_barrier(0);
#pragma unroll
      for (int u = 0; u < 8; ++u) {
        ucur = crf_step<VAR>(ucur, EX, EY, emfC[u], selx);
        emfN[u] = exp2_fast(bufN[u] * INVLN2);
      }
      renorm();
    };

    int t0 = 1;
    for (int p = 0; p < npair; ++p) {
      do_block(emfP, bufQ, emfQ, t0); t0 += 8;
      do_block(emfQ, bufP, emfP, t0); t0 += 8;
    }
    const bool odd = (nfull & 1) != 0;
    if (odd) { do_block(emfP, bufQ, emfQ, t0); t0 += 8; }

    if (tail) {
      if (odd) {
#pragma unroll
        for (int u = 0; u < 7; ++u) {
          const float nu = crf_step<VAR>(ucur, EX, EY, emfQ[u], selx);
          ucur = (u < tail) ? nu : ucur;
        }
      } else {
#pragma unroll
        for (int u = 0; u < 7; ++u) {
          const float nu = crf_step<VAR>(ucur, EX, EY, emfP[u], selx);
          ucur = (u < tail) ? nu : ucur;
        }
      }
    }

    // every tag appears exactly twice across the wave in both layouts
    const int jj = (VAR == 0) ? ((lane & 15) + 16 * (lane >> 5)) : j;
    float v = ucur * exp2_fast(end_tr[jj] * INVLN2);
#pragma unroll
    for (int m = 32; m >= 1; m >>= 1) v += __shfl_xor(v, m, 64);
    if (lane == 0) ws[b] = LN2f * (base + log2_fast(v) - 1.0f);

  } else if constexpr (SCORE) {
    const int b = blk - NSCAN;
    const int len = length[b];
    const int* tg = target + b * SLN;
    float s = 0.f;
#pragma unroll
    for (int k0 = 0; k0 < SLN; k0 += 64) {
      const int k = k0 + lane;
      if (k < len) {
        const int tk = tg[k];
        s += emission[((size_t)b * SLN + k) * TAG + tk];
        if (k >= 1) s += transition[tg[k - 1] * TAG + tk];
      }
    }
#pragma unroll
    for (int m = 32; m >= 1; m >>= 1) s += __shfl_xor(s, m, 64);
    if (lane == 0) {
      s += start_tr[tg[0]] + end_tr[tg[len - 1]];
      ws[BSZ + b] = s;
    }
  }
}

__global__ __launch_bounds__(64) void crf_reduce_kernel(const float* __restrict__ ws,
                                                        float* __restrict__ out) {
  const int lane = threadIdx.x;
  float v = (ws[lane] - ws[BSZ + lane]) + (ws[lane + 64] - ws[BSZ + lane + 64]);
#pragma unroll
  for (int m = 32; m >= 1; m >>= 1) v += __shfl_xor(v, m, 64);
  if (lane == 0) out[0] = v;
}

extern "C" void kernel_launch(void* const* d_in, const int* in_sizes, int n_in,
                              void* d_out, int out_size, void* d_ws, size_t ws_size,
                              hipStream_t stream) {
  const float* emission   = (const float*)d_in[0];
  const int*   length     = (const int*)d_in[1];
  const int*   target     = (const int*)d_in[2];
  const float* transition = (const float*)d_in[3];
  const float* start_tr   = (const float*)d_in[4];
  const float* end_tr     = (const float*)d_in[5];
  float* ws = (float*)d_ws;   // 256 floats: [0,128) logZ, [128,256) score

  // A/B round: variant A (R7 step) on batches 0-63 (+ all scores),
  // variant B (single-swap full-dot step) on batches 64-127. Separate
  // dispatches -> separate rocprof rows for a within-probe comparison.
  crf_fwd<0, 64, true><<<64 + BSZ, 64, 0, stream>>>(emission, length, target,
                                                    transition, start_tr, end_tr, ws, 0);
  crf_fwd<1, 64, false><<<64, 64, 0, stream>>>(emission, length, target,
                                               transition, start_tr, end_tr, ws, 64);
  crf_reduce_kernel<<<1, 64, 0, stream>>>(ws, (float*)d_out);
}

// Round 9
// 91.098 us; speedup vs baseline: 1.7066x; 1.7066x over previous
//
#include <hip/hip_runtime.h>

constexpr int SLN = 512, BSZ = 128, TAG = 32;
constexpr int NCH = 16, CLEN = 32;              // 16 chunks x 32 steps = 512
constexpr float INVLN2 = 1.4426950408889634f;
constexpr float LN2f = 0.6931471805599453f;

typedef float f32x16 __attribute__((ext_vector_type(16)));
typedef short bfrag  __attribute__((ext_vector_type(8)));   // 8 x bf16 (4 VGPR)
union B8 { int i[4]; bfrag v; };

// ws layout (floats): [0,128) logZ | [128,256) score | [256,2304) chunk scales
// byte 16384+: 128*16 chunk matrices, row-major bf16 32x32 (2KB each, 4MB total)
constexpr int WS_SCALE = 256;
constexpr size_t WS_MAT = 16384;

__device__ __forceinline__ float exp2_fast(float x) { return __builtin_amdgcn_exp2f(x); }
__device__ __forceinline__ float log2_fast(float x) { return __builtin_amdgcn_logf(x); }

__device__ __forceinline__ void pl32i(int& x, int& y) {
  asm("v_permlane32_swap_b32 %0, %1" : "+v"(x), "+v"(y));
}
__device__ __forceinline__ int cvtpk(float lo, float hi) {
  int r; asm("v_cvt_pk_bf16_f32 %0, %1, %2" : "=v"(r) : "v"(lo), "v"(hi)); return r;
}
__device__ __forceinline__ void gload_lds16(const float* g, float* lds_uniform) {
  __builtin_amdgcn_global_load_lds(
      (const __attribute__((address_space(1))) unsigned int*)g,
      (__attribute__((address_space(3))) unsigned int*)lds_uniform, 16, 0, 0);
}
__device__ __forceinline__ f32x16 mfma32(bfrag a, bfrag b, f32x16 c) {
  return __builtin_amdgcn_mfma_f32_32x32x16_bf16(a, b, c, 0, 0, 0);
}

template<bool PKLO>
__device__ __forceinline__ int pk2(float a, float b) {
  return PKLO ? cvtpk(a, b) : cvtpk(b, a);
}

// Build B-fragment halves from packed D rows. D lane layout (m74/m101):
// col = lane&31, row = (r&3)+8*(r>>2)+4*(lane>>5). Packs p0..p3 hold row pairs
// (4h+0,1),(4h+2,3),(8+4h+0,1),(8+4h+2,3). B-frag (k = 8*(lane>>5)+2q+{0,1})
// wants: reg0=[p0_lo|p2_lo] reg1=[p1_lo|p3_lo] reg2=[p0_hi|p2_hi] reg3=[p1_hi|p3_hi]
// (lo/hi = content of lanes 0-31 / 32-63). permlane32_swap direction is probed;
// both semantics yield the same assignment with conditional operand order.
template<bool SEM1>
__device__ __forceinline__ void mk_b(int& o0, int& o1, int& o2, int& o3,
                                     int p0, int p1, int p2, int p3) {
  if constexpr (SEM1) { pl32i(p2, p0); pl32i(p3, p1); }
  else                { pl32i(p0, p2); pl32i(p1, p3); }
  o0 = p0; o1 = p1; o2 = p2; o3 = p3;
}

// One suffix step: S <- E * (diag(emf_t) * S), with exact 2^-e renorm folded
// into the row-scale (e from exponent of S[0][0], wave-uniform pivot).
template<bool SEM1, bool PKLO>
__device__ __forceinline__ void mstep(f32x16& acc, float& base, bfrag A1, bfrag A2,
                                      float4 q0, float4 q1, float4 q2, float4 q3) {
  const int bits = __builtin_amdgcn_readfirstlane(__float_as_int(acc[0]));
  const int ex = (bits >> 23) & 255;
  const float f = __int_as_float((254 - ex) << 23);   // exact 2^-(ex-127)
  base += (float)(ex - 127);
  const int p0 = pk2<PKLO>(acc[0] * (q0.x * f),  acc[1] * (q0.y * f));
  const int p1 = pk2<PKLO>(acc[2] * (q0.z * f),  acc[3] * (q0.w * f));
  const int p2 = pk2<PKLO>(acc[4] * (q1.x * f),  acc[5] * (q1.y * f));
  const int p3 = pk2<PKLO>(acc[6] * (q1.z * f),  acc[7] * (q1.w * f));
  const int p4 = pk2<PKLO>(acc[8] * (q2.x * f),  acc[9] * (q2.y * f));
  const int p5 = pk2<PKLO>(acc[10] * (q2.z * f), acc[11] * (q2.w * f));
  const int p6 = pk2<PKLO>(acc[12] * (q3.x * f), acc[13] * (q3.y * f));
  const int p7 = pk2<PKLO>(acc[14] * (q3.z * f), acc[15] * (q3.w * f));
  B8 B1u, B2u;
  mk_b<SEM1>(B1u.i[0], B1u.i[1], B1u.i[2], B1u.i[3], p0, p1, p2, p3);
  mk_b<SEM1>(B2u.i[0], B2u.i[1], B2u.i[2], B2u.i[3], p4, p5, p6, p7);
  f32x16 z;
#pragma unroll
  for (int r = 0; r < 16; ++r) z[r] = 0.0f;
  f32x16 t = mfma32(A1, B1u.v, z);
  acc = mfma32(A2, B2u.v, t);
}

template<bool SEM1, bool PKLO>
__device__ __forceinline__ void chunk_loop(f32x16& acc, float& base, bfrag A1, bfrag A2,
                                           const float* em_s, int count, int h) {
  if (count <= 0) return;
  const float* eb = em_s + 4 * h;
  auto LDQ = [&](int tt, float4& a, float4& b, float4& c, float4& d) {
    const float* p = eb + tt * TAG;
    a = *(const float4*)(p);
    b = *(const float4*)(p + 8);
    c = *(const float4*)(p + 16);
    d = *(const float4*)(p + 24);
  };
  int tt = count - 1;                 // descending t within the chunk
  float4 a0, a1, a2, a3, b0, b1, b2, b3;
  LDQ(tt, a0, a1, a2, a3);
  LDQ(tt >= 1 ? tt - 1 : 0, b0, b1, b2, b3);
  while (tt >= 2) {
    mstep<SEM1, PKLO>(acc, base, A1, A2, a0, a1, a2, a3);
    LDQ(tt - 2, a0, a1, a2, a3);
    __builtin_amdgcn_sched_barrier(0);   // pin prefetch issue (R4/R7 lesson)
    mstep<SEM1, PKLO>(acc, base, A1, A2, b0, b1, b2, b3);
    LDQ(tt >= 3 ? tt - 3 : 0, b0, b1, b2, b3);
    __builtin_amdgcn_sched_barrier(0);
    tt -= 2;
  }
  if (tt == 1) {
    mstep<SEM1, PKLO>(acc, base, A1, A2, a0, a1, a2, a3);
    mstep<SEM1, PKLO>(acc, base, A1, A2, b0, b1, b2, b3);
  } else {
    mstep<SEM1, PKLO>(acc, base, A1, A2, a0, a1, a2, a3);
  }
}

// Kernel 1: one wave per (batch, chunk): suffix product of the chunk's
// M_t = E*diag(emf_t) matrices (identity for t beyond len-1), stored bf16.
__global__ __launch_bounds__(64) void crf_chunk(
    const float* __restrict__ emission, const int* __restrict__ length,
    const float* __restrict__ transition, float* __restrict__ ws) {
  const int blk = blockIdx.x, lane = threadIdx.x;
  const int b = blk >> 4, c = blk & 15;
  __shared__ float em_s[CLEN * TAG];   // 4KB: chunk emission rows -> emf in place
  __shared__ float tb[TAG * 36];       // padded transpose buffer (rows 144B, 16B-aligned)

  const float* gem = emission + (size_t)b * SLN * TAG;
  const int base_e = (c * CLEN + 1) * TAG;   // rows t = c*32+1 .. c*32+32
#pragma unroll
  for (int i = 0; i < 4; ++i) {
    int o = base_e + i * 256 + lane * 4;
    o = o > (SLN * TAG - 4) ? (SLN * TAG - 4) : o;   // clamp last row (t=512, unused)
    gload_lds16(gem + o, &em_s[i * 256]);
  }

  const int m = lane & 31, h = lane >> 5;

  // probes: permlane32_swap direction, cvt_pk lo/hi order
  int pv = lane, qv = lane + 64;
  pl32i(pv, qv);
  const bool sem1 = (__builtin_amdgcn_readfirstlane(pv) == 96);
  const bool pklo = ((cvtpk(1.0f, 2.0f) & 0xffff) == 0x3f80);

  // A-frags: E[m][k], k = 8h+2q+{0,1} (A1) / +16 (A2); bf16, static all steps
  B8 A1u, A2u;
#pragma unroll
  for (int q = 0; q < 4; ++q) {
    const int k0 = 8 * h + 2 * q;
    const float e0 = exp2_fast(transition[m * TAG + k0] * INVLN2);
    const float e1 = exp2_fast(transition[m * TAG + k0 + 1] * INVLN2);
    const float e2 = exp2_fast(transition[m * TAG + 16 + k0] * INVLN2);
    const float e3 = exp2_fast(transition[m * TAG + 16 + k0 + 1] * INVLN2);
    A1u.i[q] = pklo ? cvtpk(e0, e1) : cvtpk(e1, e0);
    A2u.i[q] = pklo ? cvtpk(e2, e3) : cvtpk(e3, e2);
  }

  const int len = length[b];
  int count = len - 1 - c * CLEN;
  count = count < 0 ? 0 : (count > CLEN ? CLEN : count);

  asm volatile("s_waitcnt vmcnt(0)" ::: "memory");

  // em -> emf = 2^(em*INVLN2) in place (single wave, compiler orders LDS)
  {
    float4* p = (float4*)&em_s[lane * 16];
#pragma unroll
    for (int q = 0; q < 4; ++q) {
      float4 v = p[q];
      v.x = exp2_fast(v.x * INVLN2); v.y = exp2_fast(v.y * INVLN2);
      v.z = exp2_fast(v.z * INVLN2); v.w = exp2_fast(v.w * INVLN2);
      p[q] = v;
    }
  }

  f32x16 acc;          // S in D-layout; init = identity
  float base = 0.0f;
#pragma unroll
  for (int r = 0; r < 16; ++r) {
    const int ir = (r & 3) + 8 * (r >> 2) + 4 * h;
    acc[r] = (ir == m) ? 1.0f : 0.0f;
  }

  if (sem1) {
    if (pklo) chunk_loop<true, true>(acc, base, A1u.v, A2u.v, em_s, count, h);
    else      chunk_loop<true, false>(acc, base, A1u.v, A2u.v, em_s, count, h);
  } else {
    if (pklo) chunk_loop<false, true>(acc, base, A1u.v, A2u.v, em_s, count, h);
    else      chunk_loop<false, false>(acc, base, A1u.v, A2u.v, em_s, count, h);
  }

  // transpose (lane=col -> lane=row) via padded LDS, store row-major bf16
#pragma unroll
  for (int r = 0; r < 16; ++r) {
    const int ir = (r & 3) + 8 * (r >> 2) + 4 * h;
    tb[ir * 36 + m] = acc[r];
  }
  const float* rp = &tb[m * 36 + 16 * h];   // lane stores k = 16h .. 16h+15 of row m
  const float4 r0 = *(const float4*)(rp);
  const float4 r1 = *(const float4*)(rp + 4);
  const float4 r2 = *(const float4*)(rp + 8);
  const float4 r3 = *(const float4*)(rp + 12);
  const int d0 = pklo ? cvtpk(r0.x, r0.y) : cvtpk(r0.y, r0.x);
  const int d1 = pklo ? cvtpk(r0.z, r0.w) : cvtpk(r0.w, r0.z);
  const int d2 = pklo ? cvtpk(r1.x, r1.y) : cvtpk(r1.y, r1.x);
  const int d3 = pklo ? cvtpk(r1.z, r1.w) : cvtpk(r1.w, r1.z);
  const int d4 = pklo ? cvtpk(r2.x, r2.y) : cvtpk(r2.y, r2.x);
  const int d5 = pklo ? cvtpk(r2.z, r2.w) : cvtpk(r2.w, r2.z);
  const int d6 = pklo ? cvtpk(r3.x, r3.y) : cvtpk(r3.y, r3.x);
  const int d7 = pklo ? cvtpk(r3.z, r3.w) : cvtpk(r3.w, r3.z);
  char* dst = (char*)ws + WS_MAT + (size_t)(b * NCH + c) * 2048 + m * 64 + h * 32;
  *(int4*)dst = make_int4(d0, d1, d2, d3);
  *(int4*)(dst + 16) = make_int4(d4, d5, d6, d7);
  if (lane == 0) ws[WS_SCALE + b * NCH + c] = base;
}

// Kernel 2 combine: v = C_0 * (C_1 * ... * (C_15 * endf)); logZ = log(a0 . v)
template<bool SEM1, bool PKLO>
__device__ void comb_body(int b, int lane, const float* emission,
                          const float* start_tr, const float* end_tr,
                          float* ws, float* vf) {
  const int m = lane & 31, h = lane >> 5;
  B8 B1u, B2u;   // vector rides in column 0 of the B operand
#pragma unroll
  for (int q = 0; q < 4; ++q) {
    const int k0 = 8 * h + 2 * q;
    const float e0 = exp2_fast(end_tr[k0] * INVLN2);
    const float e1 = exp2_fast(end_tr[k0 + 1] * INVLN2);
    const float e2 = exp2_fast(end_tr[16 + k0] * INVLN2);
    const float e3 = exp2_fast(end_tr[16 + k0 + 1] * INVLN2);
    const int dA = pk2<PKLO>(e0, e1), dB = pk2<PKLO>(e2, e3);
    B1u.i[q] = (m == 0) ? dA : 0;
    B2u.i[q] = (m == 0) ? dB : 0;
  }
  const char* matb = (const char*)ws + WS_MAT;
  auto LDA = [&](int c, int4& x, int4& y) {
    const char* p = matb + (size_t)(b * NCH + c) * 2048 + m * 64 + 16 * h;
    x = *(const int4*)p;          // A1: row m, k = 8h..8h+7
    y = *(const int4*)(p + 32);   // A2: row m, k = 16+8h..
  };
  float base_t = 0.0f;
  int4 xa, ya;
  LDA(NCH - 1, xa, ya);
  f32x16 D;
  for (int c = NCH - 1; c >= 0; --c) {
    int4 xn, yn;
    if (c > 0) LDA(c - 1, xn, yn);
    const float sc = ws[WS_SCALE + b * NCH + c];
    B8 Au, Av;
    Au.i[0] = xa.x; Au.i[1] = xa.y; Au.i[2] = xa.z; Au.i[3] = xa.w;
    Av.i[0] = ya.x; Av.i[1] = ya.y; Av.i[2] = ya.z; Av.i[3] = ya.w;
    f32x16 z;
#pragma unroll
    for (int r = 0; r < 16; ++r) z[r] = 0.0f;
    f32x16 t = mfma32(Au.v, B1u.v, z);
    D = mfma32(Av.v, B2u.v, t);
    const int bits = __builtin_amdgcn_readfirstlane(__float_as_int(D[0]));
    const int ex = (bits >> 23) & 255;
    const float f = __int_as_float((254 - ex) << 23);
    base_t += (float)(ex - 127) + sc;
#pragma unroll
    for (int r = 0; r < 16; ++r) D[r] *= f;
    if (c > 0) {
      const int p0 = pk2<PKLO>(D[0], D[1]);
      const int p1 = pk2<PKLO>(D[2], D[3]);
      const int p2 = pk2<PKLO>(D[4], D[5]);
      const int p3 = pk2<PKLO>(D[6], D[7]);
      const int p4 = pk2<PKLO>(D[8], D[9]);
      const int p5 = pk2<PKLO>(D[10], D[11]);
      const int p6 = pk2<PKLO>(D[12], D[13]);
      const int p7 = pk2<PKLO>(D[14], D[15]);
      mk_b<SEM1>(B1u.i[0], B1u.i[1], B1u.i[2], B1u.i[3], p0, p1, p2, p3);
      mk_b<SEM1>(B2u.i[0], B2u.i[1], B2u.i[2], B2u.i[3], p4, p5, p6, p7);
      xa = xn; ya = yn;
    }
  }
  if (m == 0) {   // lanes 0 & 32 hold column 0 = final vector
#pragma unroll
    for (int r = 0; r < 16; ++r) vf[(r & 3) + 8 * (r >> 2) + 4 * h] = D[r];
  }
  const float a0 = exp2_fast((start_tr[m] + emission[(size_t)b * SLN * TAG + m]) * INVLN2);
  float vsum = (lane < 32) ? vf[m] * a0 : 0.0f;
#pragma unroll
  for (int mm = 32; mm >= 1; mm >>= 1) vsum += __shfl_xor(vsum, mm, 64);
  if (lane == 0) ws[b] = LN2f * (log2_fast(vsum) + base_t);
}

__global__ __launch_bounds__(64) void crf_comb(
    const float* __restrict__ emission, const int* __restrict__ length,
    const int* __restrict__ target, const float* __restrict__ transition,
    const float* __restrict__ start_tr, const float* __restrict__ end_tr,
    float* __restrict__ ws) {
  const int blk = blockIdx.x, lane = threadIdx.x;
  __shared__ float vf[TAG];
  if (blk < BSZ) {
    int pv = lane, qv = lane + 64;
    pl32i(pv, qv);
    const bool sem1 = (__builtin_amdgcn_readfirstlane(pv) == 96);
    const bool pklo = ((cvtpk(1.0f, 2.0f) & 0xffff) == 0x3f80);
    if (sem1) {
      if (pklo) comb_body<true, true>(blk, lane, emission, start_tr, end_tr, ws, vf);
      else      comb_body<true, false>(blk, lane, emission, start_tr, end_tr, ws, vf);
    } else {
      if (pklo) comb_body<false, true>(blk, lane, emission, start_tr, end_tr, ws, vf);
      else      comb_body<false, false>(blk, lane, emission, start_tr, end_tr, ws, vf);
    }
  } else {
    const int b = blk - BSZ;
    const int len = length[b];
    const int* tg = target + b * SLN;
    float s = 0.f;
#pragma unroll
    for (int k0 = 0; k0 < SLN; k0 += 64) {
      const int k = k0 + lane;
      if (k < len) {
        const int tk = tg[k];
        s += emission[((size_t)b * SLN + k) * TAG + tk];
        if (k >= 1) s += transition[tg[k - 1] * TAG + tk];
      }
    }
#pragma unroll
    for (int mm = 32; mm >= 1; mm >>= 1) s += __shfl_xor(s, mm, 64);
    if (lane == 0) {
      s += start_tr[tg[0]] + end_tr[tg[len - 1]];
      ws[BSZ + b] = s;
    }
  }
}

__global__ __launch_bounds__(64) void crf_reduce_kernel(const float* __restrict__ ws,
                                                        float* __restrict__ out) {
  const int lane = threadIdx.x;
  float v = (ws[lane] - ws[BSZ + lane]) + (ws[lane + 64] - ws[BSZ + lane + 64]);
#pragma unroll
  for (int m = 32; m >= 1; m >>= 1) v += __shfl_xor(v, m, 64);
  if (lane == 0) out[0] = v;
}

extern "C" void kernel_launch(void* const* d_in, const int* in_sizes, int n_in,
                              void* d_out, int out_size, void* d_ws, size_t ws_size,
                              hipStream_t stream) {
  const float* emission   = (const float*)d_in[0];
  const int*   length     = (const int*)d_in[1];
  const int*   target     = (const int*)d_in[2];
  const float* transition = (const float*)d_in[3];
  const float* start_tr   = (const float*)d_in[4];
  const float* end_tr     = (const float*)d_in[5];
  float* ws = (float*)d_ws;

  crf_chunk<<<BSZ * NCH, 64, 0, stream>>>(emission, length, transition, ws);
  crf_comb<<<2 * BSZ, 64, 0, stream>>>(emission, length, target, transition,
                                       start_tr, end_tr, ws);
  crf_reduce_kernel<<<1, 64, 0, stream>>>(ws, (float*)d_out);
}